// Round 8
// baseline (214.187 us; speedup 1.0000x reference)
//
#include <hip/hip_runtime.h>
#include <hip/hip_cooperative_groups.h>
#include <math.h>
#include <stdint.h>

namespace cg = cooperative_groups;

// GE2E loss on MI355X — single cooperative kernel, 4 phases.
// out = sum_k counts[k]*log(sum_j exp(S[j,k])) - sum_i logit_self[i]
// Logits <= w*1+b = 5 -> exp without max-subtraction is safe in fp32.
// Phase1: per-class ballot-gather centroid (block=class), normalize rows -> ebf bf16.
// Phase2: MFMA GEMM ebf @ csum^T, BM=64 BN=256(all C) BK=64, 8 waves, dbuf gload_lds.
// Phase3: per-class column reduce -> contrib[c]. Phase4: block0 final sum -> out.
// Self logit: u = csum_y - e; dot(e,u)=dot-1; |u|^2 = nsq - 2*dot + 1.

typedef __attribute__((ext_vector_type(8))) short bf16x8;
typedef __attribute__((ext_vector_type(4))) float f32x4;
struct alignas(16) US8 { unsigned short u[8]; };

__device__ inline float waveReduceSum(float v) {
#pragma unroll
    for (int m = 32; m >= 1; m >>= 1) v += __shfl_xor(v, m, 64);
    return v;
}
__device__ inline unsigned short f2bf(float f) {
    uint32_t u = __float_as_uint(f);
    return (unsigned short)((u + 0x7FFFu + ((u >> 16) & 1u)) >> 16);
}
__device__ inline void gload_lds16(const void* g, void* l) {
    __builtin_amdgcn_global_load_lds(
        (const __attribute__((address_space(1))) uint32_t*)g,
        (__attribute__((address_space(3))) uint32_t*)l, 16, 0, 0);
}

#define NKT 8
#define SMEM_BYTES 82976

__global__ __launch_bounds__(512, 2) void k_all(
        const float* __restrict__ emb, const int* __restrict__ y,
        const float* __restrict__ wptr, const float* __restrict__ bptr,
        unsigned short* __restrict__ ebf, unsigned short* __restrict__ csum_bf,
        float* __restrict__ colpart, float* __restrict__ selfpart,
        float* __restrict__ normsq, float* __restrict__ colscale,
        int* __restrict__ counts, float* __restrict__ contrib,
        float* __restrict__ out, int N) {
    __shared__ __align__(16) char smem[SMEM_BYTES];
    cg::grid_group grid = cg::this_grid();

    const int tid = threadIdx.x;
    const int l = tid & 63;
    const int w = tid >> 6;
    const int bx = blockIdx.x;

    // ============ Phase 1: centroid (block = class c) ============
    {
        float (*part)[512] = (float(*)[512])smem;
        float* red = (float*)(smem + 16384);
        int* cnts = (int*)(smem + 18432);
        int c = bx;
        int chunk = N >> 3;
        float facc[8] = {0.f, 0.f, 0.f, 0.f, 0.f, 0.f, 0.f, 0.f};
        int cnt = 0;
        int iend = (w + 1) * chunk;
        for (int i0 = w * chunk; i0 < iend; i0 += 64) {
            unsigned long long m = __ballot(y[i0 + l] == c);
            cnt += (int)__popcll(m);
            while (m) {                       // wave-uniform mask
                int b = __builtin_ctzll(m);
                m &= m - 1;
                int r = i0 + b;
                const float4* pr = reinterpret_cast<const float4*>(emb + (size_t)r * 512);
                float4 v0 = pr[l * 2], v1 = pr[l * 2 + 1];
                float s = v0.x * v0.x + v0.y * v0.y + v0.z * v0.z + v0.w * v0.w
                        + v1.x * v1.x + v1.y * v1.y + v1.z * v1.z + v1.w * v1.w;
                s = waveReduceSum(s);
                float inv = 1.0f / fmaxf(sqrtf(s), 1e-12f);
                float e0 = v0.x * inv, e1 = v0.y * inv, e2 = v0.z * inv, e3 = v0.w * inv;
                float e4 = v1.x * inv, e5 = v1.y * inv, e6 = v1.z * inv, e7 = v1.w * inv;
                US8 t;
                t.u[0] = f2bf(e0); t.u[1] = f2bf(e1); t.u[2] = f2bf(e2); t.u[3] = f2bf(e3);
                t.u[4] = f2bf(e4); t.u[5] = f2bf(e5); t.u[6] = f2bf(e6); t.u[7] = f2bf(e7);
                *reinterpret_cast<US8*>(ebf + (size_t)r * 512 + l * 8) = t;
                facc[0] += e0; facc[1] += e1; facc[2] += e2; facc[3] += e3;
                facc[4] += e4; facc[5] += e5; facc[6] += e6; facc[7] += e7;
            }
        }
        *reinterpret_cast<float4*>(&part[w][l * 8]) =
            make_float4(facc[0], facc[1], facc[2], facc[3]);
        *reinterpret_cast<float4*>(&part[w][l * 8 + 4]) =
            make_float4(facc[4], facc[5], facc[6], facc[7]);
        if (l == 0) cnts[w] = cnt;
        __syncthreads();
        float s = part[0][tid] + part[1][tid] + part[2][tid] + part[3][tid]
                + part[4][tid] + part[5][tid] + part[6][tid] + part[7][tid];
        csum_bf[(size_t)c * 512 + tid] = f2bf(s);
        red[tid] = s * s;
        __syncthreads();
        for (int o = 256; o >= 1; o >>= 1) {
            if (tid < o) red[tid] += red[tid + o];
            __syncthreads();
        }
        if (tid == 0) {
            int ct = cnts[0] + cnts[1] + cnts[2] + cnts[3]
                   + cnts[4] + cnts[5] + cnts[6] + cnts[7];
            counts[c] = ct;
            float nsq = red[0];
            normsq[c] = nsq;
            colscale[c] = wptr[0] / fmaxf(sqrtf(nsq), (float)ct * 1e-8f);
        }
    }
    __threadfence();
    grid.sync();

    // ============ Phase 2: GEMM row-tile bx (64 rows x 256 cols) ============
    {
        unsigned short (*As)[4096]  = (unsigned short(*)[4096])smem;            // 2 x 8KB
        unsigned short (*Bs)[16384] = (unsigned short(*)[16384])(smem + 16384); // 2 x 32KB
        float* colsum  = (float*)(smem + 81920);   // 256 floats
        float* selfred = (float*)(smem + 82944);   // 8 floats

        const int r0 = bx * 64;
        const int rsub = l >> 2;
        const int kcs = ((l & 3) ^ ((l >> 3) & 3)) * 8;

        // A: 8 subtiles (kh*4 + rowblk); wave w stages subtile w.
        const unsigned short* srcA = ebf + (size_t)(r0 + (w & 3) * 16 + rsub) * 512
                                   + (w >> 2) * 32 + kcs;
        // B: 32 subtiles (kh*16 + colblk); wave w stages subtiles w*4..w*4+3.
        const unsigned short* srcB[4];
#pragma unroll
        for (int i = 0; i < 4; ++i) {
            int st = w * 4 + i;
            srcB[i] = csum_bf + (size_t)((st & 15) * 16 + rsub) * 512 + (st >> 4) * 32 + kcs;
        }
        const int fro = (l & 15) * 32 + (((l >> 4) ^ ((l >> 1) & 3)) * 8);

        f32x4 acc[4][2];
#pragma unroll
        for (int m = 0; m < 4; ++m)
#pragma unroll
            for (int n = 0; n < 2; ++n) acc[m][n] = (f32x4){0.f, 0.f, 0.f, 0.f};

        gload_lds16(srcA, &As[0][w * 512]);
#pragma unroll
        for (int i = 0; i < 4; ++i) gload_lds16(srcB[i], &Bs[0][(w * 4 + i) * 512]);
        __syncthreads();

        int cur = 0;
        for (int kt = 0; kt < NKT; ++kt) {
            if (kt + 1 < NKT) {
                gload_lds16(srcA + (kt + 1) * 64, &As[cur ^ 1][w * 512]);
#pragma unroll
                for (int i = 0; i < 4; ++i)
                    gload_lds16(srcB[i] + (kt + 1) * 64, &Bs[cur ^ 1][(w * 4 + i) * 512]);
            }
#pragma unroll
            for (int h = 0; h < 2; ++h) {
                bf16x8 af[4];
#pragma unroll
                for (int m = 0; m < 4; ++m)
                    af[m] = *reinterpret_cast<const bf16x8*>(&As[cur][(h * 4 + m) * 512 + fro]);
#pragma unroll
                for (int n = 0; n < 2; ++n) {
                    bf16x8 bv = *reinterpret_cast<const bf16x8*>(
                        &Bs[cur][(h * 16 + w * 2 + n) * 512 + fro]);
#pragma unroll
                    for (int m = 0; m < 4; ++m)
                        acc[m][n] = __builtin_amdgcn_mfma_f32_16x16x32_bf16(af[m], bv, acc[m][n], 0, 0, 0);
                }
            }
            __syncthreads();
            cur ^= 1;
        }

        // epilogue: C/D layout col=lane&15, row=(lane>>4)*4+j; wave w -> cols w*32..+31
        float bv = bptr[0], wv = wptr[0];
        int lcol = l & 15, lrow4 = (l >> 4) * 4;
        float cs[2], nsq[2], cm1[2]; int cls[2];
#pragma unroll
        for (int n = 0; n < 2; ++n) {
            int c = w * 32 + n * 16 + lcol;
            cls[n] = c; cs[n] = colscale[c]; nsq[n] = normsq[c];
            cm1[n] = (float)(counts[c] - 1);
        }
        float colacc[2] = {0.f, 0.f};
        float selfacc = 0.f;
#pragma unroll
        for (int m = 0; m < 4; ++m) {
#pragma unroll
            for (int j = 0; j < 4; ++j) {
                int row = r0 + m * 16 + lrow4 + j;
                int yc = y[row];
#pragma unroll
                for (int n = 0; n < 2; ++n) {
                    float dot = acc[m][n][j];
                    float logit;
                    if (yc == cls[n]) {
                        float un2 = fmaxf(nsq[n] - 2.f * dot + 1.f, 0.f);
                        float denom = fmaxf(sqrtf(un2), cm1[n] * 1e-8f);
                        logit = wv * (dot - 1.f) / denom + bv;
                        selfacc += logit;
                    } else {
                        logit = dot * cs[n] + bv;
                    }
                    colacc[n] += __expf(logit);
                }
            }
        }
#pragma unroll
        for (int n = 0; n < 2; ++n) {
            float v = colacc[n];
            v += __shfl_xor(v, 16, 64);
            v += __shfl_xor(v, 32, 64);
            colacc[n] = v;
        }
        selfacc = waveReduceSum(selfacc);
        if (l < 16) {
#pragma unroll
            for (int n = 0; n < 2; ++n) colsum[w * 32 + n * 16 + l] = colacc[n];
        }
        if (l == 0) selfred[w] = selfacc;
        __syncthreads();
        if (tid < 256)
            colpart[(size_t)bx * 256 + tid] = colsum[tid];
        if (tid == 0)
            selfpart[bx] = selfred[0] + selfred[1] + selfred[2] + selfred[3]
                         + selfred[4] + selfred[5] + selfred[6] + selfred[7];
    }
    __threadfence();
    grid.sync();

    // ============ Phase 3: per-class reduce -> contrib[c] ============
    {
        float* red = (float*)smem;   // 512 floats
        int c = bx;
        float s = (tid < 256) ? colpart[(size_t)tid * 256 + c] : 0.f;
        red[tid] = s;
        __syncthreads();
        for (int o = 256; o >= 1; o >>= 1) {
            if (tid < o) red[tid] += red[tid + o];
            __syncthreads();
        }
        if (tid == 0) contrib[c] = (float)counts[c] * logf(red[0]);
    }
    __threadfence();
    grid.sync();

    // ============ Phase 4: block 0 finalize ============
    if (bx == 0) {
        float* red = (float*)smem;
        float v = 0.f;
        if (tid < 256) v = contrib[tid] - selfpart[tid];
        red[tid] = v;
        __syncthreads();
        for (int o = 256; o >= 1; o >>= 1) {
            if (tid < o) red[tid] += red[tid + o];
            __syncthreads();
        }
        if (tid == 0) out[0] = red[0];
    }
}

extern "C" void kernel_launch(void* const* d_in, const int* in_sizes, int n_in,
                              void* d_out, int out_size, void* d_ws, size_t ws_size,
                              hipStream_t stream) {
    const float* emb  = (const float*)d_in[0];
    const int*   y    = (const int*)d_in[1];
    const float* wptr = (const float*)d_in[2];
    const float* bptr = (const float*)d_in[3];
    float* out = (float*)d_out;
    int N = in_sizes[1];                      // 16384
    const int C = 256;
    int D = in_sizes[0] / N;                  // 512
    (void)D;
    int nbx = N / 64;                         // 256 blocks

    unsigned short* ebf     = (unsigned short*)d_ws;                 // N*512 bf16
    unsigned short* csum_bf = ebf + (size_t)N * 512;                 // C*512 bf16
    float* colpart  = (float*)(csum_bf + (size_t)C * 512);           // nbx*C
    float* selfpart = colpart + (size_t)nbx * C;                     // nbx
    float* normsq   = selfpart + nbx;                                // C
    float* colscale = normsq + C;                                    // C
    int*   counts   = (int*)(colscale + C);                          // C
    float* contrib  = (float*)(counts + C);                          // C

    void* args[] = { (void*)&emb, (void*)&y, (void*)&wptr, (void*)&bptr,
                     (void*)&ebf, (void*)&csum_bf, (void*)&colpart, (void*)&selfpart,
                     (void*)&normsq, (void*)&colscale, (void*)&counts, (void*)&contrib,
                     (void*)&out, (void*)&N };
    (void)hipLaunchCooperativeKernel((const void*)k_all, dim3(nbx), dim3(512),
                                     args, 0, stream);
}

// Round 9
// 130.696 us; speedup vs baseline: 1.6388x; 1.6388x over previous
//
#include <hip/hip_runtime.h>
#include <math.h>
#include <stdint.h>

// GE2E loss on MI355X — 2-kernel pipeline.
// out = sum_k counts[k]*log(sum_j exp(S[j,k])) - sum_i logit_self[i]
// Logits <= w*1+b = 5 -> exp without max-subtraction is safe in fp32.
// K1: per-class ballot-gather centroid (block=class); normalizes rows from fp32 emb
//     in-wave, writes bf16 ebf (each row exactly once) + csum_bf/normsq/colscale/counts.
//     Also resets K2's ticket counter (stream order guarantees visibility).
// K2: MFMA GEMM ebf @ csum^T (BM=64, BN=256=all classes, BK=64, 8 waves, double-buffered
//     global_load_lds) + fused self-logit/exp/col-partials; last block (device ticket)
//     deterministically reduces colpart/selfpart -> out.
// Self logit: u = csum_y - e; dot(e,u)=dot-1; |u|^2 = nsq - 2*dot + 1.

typedef __attribute__((ext_vector_type(8))) short bf16x8;
typedef __attribute__((ext_vector_type(4))) float f32x4;
struct alignas(16) US8 { unsigned short u[8]; };

__device__ inline float waveReduceSum(float v) {
#pragma unroll
    for (int m = 32; m >= 1; m >>= 1) v += __shfl_xor(v, m, 64);
    return v;
}
__device__ inline unsigned short f2bf(float f) {
    uint32_t u = __float_as_uint(f);
    return (unsigned short)((u + 0x7FFFu + ((u >> 16) & 1u)) >> 16);
}
__device__ inline void gload_lds16(const void* g, void* l) {
    __builtin_amdgcn_global_load_lds(
        (const __attribute__((address_space(1))) uint32_t*)g,
        (__attribute__((address_space(3))) uint32_t*)l, 16, 0, 0);
}

// --- K1: fused normalize + per-class centroid (block per class, 8 waves) ---
__global__ __launch_bounds__(512) void k_centroid(
        const float* __restrict__ emb, const int* __restrict__ y,
        const float* __restrict__ wptr, unsigned short* __restrict__ ebf,
        unsigned short* __restrict__ csum_bf, float* __restrict__ normsq,
        float* __restrict__ colscale, int* __restrict__ counts,
        int* __restrict__ ticket, int N) {
    __shared__ float part[8][512];
    __shared__ float red[512];
    __shared__ int cnts[8];
    int c = blockIdx.x;
    int tid = threadIdx.x, l = tid & 63, w = tid >> 6;
    if (c == 0 && tid == 0) *ticket = 0;      // reset K2's ticket every call
    int chunk = N >> 3;                       // rows per wave (2048)
    float facc[8] = {0.f, 0.f, 0.f, 0.f, 0.f, 0.f, 0.f, 0.f};
    int cnt = 0;
    int iend = (w + 1) * chunk;
    for (int i0 = w * chunk; i0 < iend; i0 += 256) {
        int4 y4 = *reinterpret_cast<const int4*>(y + i0 + l * 4);
#pragma unroll
        for (int comp = 0; comp < 4; ++comp) {
            int yv = (comp == 0) ? y4.x : (comp == 1) ? y4.y : (comp == 2) ? y4.z : y4.w;
            unsigned long long m = __ballot(yv == c);
            cnt += (int)__popcll(m);
            while (m) {                        // wave-uniform mask
                int b = __builtin_ctzll(m);
                m &= m - 1;
                int r = i0 + 4 * b + comp;
                const float4* pr = reinterpret_cast<const float4*>(emb + (size_t)r * 512);
                float4 v0 = pr[l * 2], v1 = pr[l * 2 + 1];
                float s = v0.x * v0.x + v0.y * v0.y + v0.z * v0.z + v0.w * v0.w
                        + v1.x * v1.x + v1.y * v1.y + v1.z * v1.z + v1.w * v1.w;
                s = waveReduceSum(s);
                float inv = 1.0f / fmaxf(sqrtf(s), 1e-12f);
                float e0 = v0.x * inv, e1 = v0.y * inv, e2 = v0.z * inv, e3 = v0.w * inv;
                float e4 = v1.x * inv, e5 = v1.y * inv, e6 = v1.z * inv, e7 = v1.w * inv;
                US8 t;
                t.u[0] = f2bf(e0); t.u[1] = f2bf(e1); t.u[2] = f2bf(e2); t.u[3] = f2bf(e3);
                t.u[4] = f2bf(e4); t.u[5] = f2bf(e5); t.u[6] = f2bf(e6); t.u[7] = f2bf(e7);
                *reinterpret_cast<US8*>(ebf + (size_t)r * 512 + l * 8) = t;
                facc[0] += e0; facc[1] += e1; facc[2] += e2; facc[3] += e3;
                facc[4] += e4; facc[5] += e5; facc[6] += e6; facc[7] += e7;
            }
        }
    }
    *reinterpret_cast<float4*>(&part[w][l * 8]) =
        make_float4(facc[0], facc[1], facc[2], facc[3]);
    *reinterpret_cast<float4*>(&part[w][l * 8 + 4]) =
        make_float4(facc[4], facc[5], facc[6], facc[7]);
    if (l == 0) cnts[w] = cnt;
    __syncthreads();
    float s = part[0][tid] + part[1][tid] + part[2][tid] + part[3][tid]
            + part[4][tid] + part[5][tid] + part[6][tid] + part[7][tid];
    csum_bf[(size_t)c * 512 + tid] = f2bf(s);
    red[tid] = s * s;
    __syncthreads();
    for (int o = 256; o >= 1; o >>= 1) {
        if (tid < o) red[tid] += red[tid + o];
        __syncthreads();
    }
    if (tid == 0) {
        int ct = cnts[0] + cnts[1] + cnts[2] + cnts[3]
               + cnts[4] + cnts[5] + cnts[6] + cnts[7];
        counts[c] = ct;
        float nsq = red[0];
        normsq[c] = nsq;
        colscale[c] = wptr[0] / fmaxf(sqrtf(nsq), (float)ct * 1e-8f);
    }
}

// --- K2: GEMM (64 rows x 256 cols per block, 8 waves) + last-block finalize ---
#define NKT 8

__global__ __launch_bounds__(512) void k_gemm(
        const unsigned short* __restrict__ ebf, const unsigned short* __restrict__ csum_bf,
        const int* __restrict__ y, const float* __restrict__ colscale,
        const float* __restrict__ normsq, const int* __restrict__ counts,
        const float* __restrict__ wptr, const float* __restrict__ bptr,
        float* __restrict__ colpart, float* __restrict__ selfpart,
        int* __restrict__ ticket, float* __restrict__ out, int C) {
    __shared__ __align__(16) unsigned short As[2][8 * 512];    // 2 x 8 KB
    __shared__ __align__(16) unsigned short Bs[2][16 * 2048 / 2]; // placeholder sizing below
    // NOTE: Bs actually [2][16*1024]? -- defined properly:
    // (we keep explicit sizes to stay within 160KB)
    __shared__ float colsum[256];
    __shared__ float selfred[8];
    __shared__ int lastflag;

    const int tid = threadIdx.x;
    const int l = tid & 63;
    const int w = tid >> 6;
    const int bx = blockIdx.x;
    const int nbx = gridDim.x;
    const int r0 = bx * 64;
    const int rsub = l >> 2;
    const int kcs = ((l & 3) ^ ((l >> 3) & 3)) * 8;

    // A: 8 subtiles (kh*4 + rowblk); wave w stages subtile w.
    const unsigned short* srcA = ebf + (size_t)(r0 + (w & 3) * 16 + rsub) * 512
                               + (w >> 2) * 32 + kcs;
    // B: 32 subtiles (kh*16 + colblk); wave w stages subtiles w*4..w*4+3.
    const unsigned short* srcB[4];
#pragma unroll
    for (int i = 0; i < 4; ++i) {
        int st = w * 4 + i;
        srcB[i] = csum_bf + (size_t)((st & 15) * 16 + rsub) * 512 + (st >> 4) * 32 + kcs;
    }
    const int fro = (l & 15) * 32 + (((l >> 4) ^ ((l >> 1) & 3)) * 8);

    f32x4 acc[4][2];
#pragma unroll
    for (int m = 0; m < 4; ++m)
#pragma unroll
        for (int n = 0; n < 2; ++n) acc[m][n] = (f32x4){0.f, 0.f, 0.f, 0.f};

    gload_lds16(srcA, &As[0][w * 512]);
#pragma unroll
    for (int i = 0; i < 4; ++i) gload_lds16(srcB[i], &Bs[0][(w * 4 + i) * 512]);
    __syncthreads();

    int cur = 0;
    for (int kt = 0; kt < NKT; ++kt) {
        if (kt + 1 < NKT) {
            gload_lds16(srcA + (kt + 1) * 64, &As[cur ^ 1][w * 512]);
#pragma unroll
            for (int i = 0; i < 4; ++i)
                gload_lds16(srcB[i] + (kt + 1) * 64, &Bs[cur ^ 1][(w * 4 + i) * 512]);
        }
#pragma unroll
        for (int h = 0; h < 2; ++h) {
            bf16x8 af[4];
#pragma unroll
            for (int m = 0; m < 4; ++m)
                af[m] = *reinterpret_cast<const bf16x8*>(&As[cur][(h * 4 + m) * 512 + fro]);
#pragma unroll
            for (int n = 0; n < 2; ++n) {
                bf16x8 bv = *reinterpret_cast<const bf16x8*>(
                    &Bs[cur][(h * 16 + w * 2 + n) * 512 + fro]);
#pragma unroll
                for (int m = 0; m < 4; ++m)
                    acc[m][n] = __builtin_amdgcn_mfma_f32_16x16x32_bf16(af[m], bv, acc[m][n], 0, 0, 0);
            }
        }
        __syncthreads();
        cur ^= 1;
    }

    // epilogue: C/D layout col=lane&15, row=(lane>>4)*4+j; wave w -> cols w*32..+31
    float bv = bptr[0], wv = wptr[0];
    int lcol = l & 15, lrow4 = (l >> 4) * 4;
    float cs[2], nsq[2], cm1[2]; int cls[2];
#pragma unroll
    for (int n = 0; n < 2; ++n) {
        int c = w * 32 + n * 16 + lcol;
        cls[n] = c; cs[n] = colscale[c]; nsq[n] = normsq[c];
        cm1[n] = (float)(counts[c] - 1);
    }
    float colacc[2] = {0.f, 0.f};
    float selfacc = 0.f;
#pragma unroll
    for (int m = 0; m < 4; ++m) {
#pragma unroll
        for (int j = 0; j < 4; ++j) {
            int row = r0 + m * 16 + lrow4 + j;
            int yc = y[row];
#pragma unroll
            for (int n = 0; n < 2; ++n) {
                float dot = acc[m][n][j];
                float logit;
                if (yc == cls[n]) {
                    float un2 = fmaxf(nsq[n] - 2.f * dot + 1.f, 0.f);
                    float denom = fmaxf(sqrtf(un2), cm1[n] * 1e-8f);
                    logit = wv * (dot - 1.f) / denom + bv;
                    selfacc += logit;
                } else {
                    logit = dot * cs[n] + bv;
                }
                colacc[n] += __expf(logit);
            }
        }
    }
#pragma unroll
    for (int n = 0; n < 2; ++n) {
        float v = colacc[n];
        v += __shfl_xor(v, 16, 64);
        v += __shfl_xor(v, 32, 64);
        colacc[n] = v;
    }
    selfacc = waveReduceSum(selfacc);
    if (l < 16) {
#pragma unroll
        for (int n = 0; n < 2; ++n) colsum[w * 32 + n * 16 + l] = colacc[n];
    }
    if (l == 0) selfred[w] = selfacc;
    __syncthreads();
    if (tid < 256)
        colpart[(size_t)bx * 256 + tid] = colsum[tid];
    if (tid == 0)
        selfpart[bx] = selfred[0] + selfred[1] + selfred[2] + selfred[3]
                     + selfred[4] + selfred[5] + selfred[6] + selfred[7];

    // ---- last-block deterministic finalize ----
    __threadfence();           // make colpart/selfpart visible device-wide
    if (tid == 0) {
        int t = atomicAdd(ticket, 1);
        lastflag = (t == nbx - 1);
    }
    __syncthreads();
    if (!lastflag) return;
    __threadfence();           // acquire: order subsequent loads

    float* red = (float*)&As[0][0];   // reuse LDS (all prior uses synced)
    float v = 0.f;
    if (tid < 256) {
        int c = tid;
        float s = 0.f;
        for (int i = 0; i < nbx; ++i) s += colpart[(size_t)i * 256 + c];  // coalesced
        v = (float)counts[c] * logf(s);
    } else {
        int i = tid - 256;
        if (i < nbx) v = -selfpart[i];
        for (i += 256; i < nbx; i += 256) v -= selfpart[i];
    }
    red[tid] = v;
    __syncthreads();
    for (int o = 256; o >= 1; o >>= 1) {
        if (tid < o) red[tid] += red[tid + o];
        __syncthreads();
    }
    if (tid == 0) out[0] = red[0];
}

extern "C" void kernel_launch(void* const* d_in, const int* in_sizes, int n_in,
                              void* d_out, int out_size, void* d_ws, size_t ws_size,
                              hipStream_t stream) {
    const float* emb  = (const float*)d_in[0];
    const int*   y    = (const int*)d_in[1];
    const float* wptr = (const float*)d_in[2];
    const float* bptr = (const float*)d_in[3];
    float* out = (float*)d_out;
    int N = in_sizes[1];                      // 16384
    const int C = 256;
    int nbx = N / 64;                         // 256

    unsigned short* ebf     = (unsigned short*)d_ws;                 // N*512 bf16
    unsigned short* csum_bf = ebf + (size_t)N * 512;                 // C*512 bf16
    float* colpart  = (float*)(csum_bf + (size_t)C * 512);           // nbx*C
    float* selfpart = colpart + (size_t)nbx * C;                     // nbx
    float* normsq   = selfpart + nbx;                                // C
    float* colscale = normsq + C;                                    // C
    int*   counts   = (int*)(colscale + C);                          // C
    int*   ticket   = counts + C;                                    // 1

    k_centroid<<<C, 512, 0, stream>>>(emb, y, wptr, ebf, csum_bf, normsq,
                                      colscale, counts, ticket, N);
    k_gemm    <<<nbx, 512, 0, stream>>>(ebf, csum_bf, y, colscale, normsq, counts,
                                        wptr, bptr, colpart, selfpart, ticket, out, C);
}

// Round 10
// 38.423 us; speedup vs baseline: 5.5745x; 3.4016x over previous
//
#include <hip/hip_runtime.h>
#include <math.h>
#include <stdint.h>

// GE2E loss on MI355X — 4-kernel pipeline, no memsets, no device fences.
// out = sum_k counts[k]*log(sum_j exp(S[j,k])) - sum_i logit_self[i]
// Logits <= w*1+b = 5 -> exp without max-subtraction is safe in fp32.
// K1: per-class ballot-gather centroid (block=class); normalizes rows in-wave,
//     writes bf16 ebf (each row exactly once) + csum_bf/normsq/colscale/counts.
// K2: MFMA GEMM ebf @ csum^T (BM=64, BN=256=all classes, BK=64, 8 waves,
//     double-buffered global_load_lds) + fused self-logit/exp/col-partials.
// K3: per-class reduce -> contrib[c].  K4: final sum -> out.
// Self logit: u = csum_y - e; dot(e,u)=dot-1; |u|^2 = nsq - 2*dot + 1.

typedef __attribute__((ext_vector_type(8))) short bf16x8;
typedef __attribute__((ext_vector_type(4))) float f32x4;
struct alignas(16) US8 { unsigned short u[8]; };

__device__ inline float waveReduceSum(float v) {
#pragma unroll
    for (int m = 32; m >= 1; m >>= 1) v += __shfl_xor(v, m, 64);
    return v;
}
__device__ inline unsigned short f2bf(float f) {
    uint32_t u = __float_as_uint(f);
    return (unsigned short)((u + 0x7FFFu + ((u >> 16) & 1u)) >> 16);
}
__device__ inline void gload_lds16(const void* g, void* l) {
    __builtin_amdgcn_global_load_lds(
        (const __attribute__((address_space(1))) uint32_t*)g,
        (__attribute__((address_space(3))) uint32_t*)l, 16, 0, 0);
}

// --- K1: fused normalize + per-class centroid (block per class, 8 waves) ---
__global__ __launch_bounds__(512) void k_centroid(
        const float* __restrict__ emb, const int* __restrict__ y,
        const float* __restrict__ wptr, unsigned short* __restrict__ ebf,
        unsigned short* __restrict__ csum_bf, float* __restrict__ normsq,
        float* __restrict__ colscale, int* __restrict__ counts, int N) {
    __shared__ float part[8][512];
    __shared__ float red[512];
    __shared__ int cnts[8];
    int c = blockIdx.x;
    int tid = threadIdx.x, l = tid & 63, w = tid >> 6;
    int chunk = N >> 3;                       // rows per wave (2048)
    float facc[8] = {0.f, 0.f, 0.f, 0.f, 0.f, 0.f, 0.f, 0.f};
    int cnt = 0;
    int iend = (w + 1) * chunk;
    for (int i0 = w * chunk; i0 < iend; i0 += 256) {
        int4 y4 = *reinterpret_cast<const int4*>(y + i0 + l * 4);
#pragma unroll
        for (int comp = 0; comp < 4; ++comp) {
            int yv = (comp == 0) ? y4.x : (comp == 1) ? y4.y : (comp == 2) ? y4.z : y4.w;
            unsigned long long m = __ballot(yv == c);
            cnt += (int)__popcll(m);
            while (m) {                        // wave-uniform mask
                int b = __builtin_ctzll(m);
                m &= m - 1;
                int r = i0 + 4 * b + comp;
                const float4* pr = reinterpret_cast<const float4*>(emb + (size_t)r * 512);
                float4 v0 = pr[l * 2], v1 = pr[l * 2 + 1];
                float s = v0.x * v0.x + v0.y * v0.y + v0.z * v0.z + v0.w * v0.w
                        + v1.x * v1.x + v1.y * v1.y + v1.z * v1.z + v1.w * v1.w;
                s = waveReduceSum(s);
                float inv = 1.0f / fmaxf(sqrtf(s), 1e-12f);
                float e0 = v0.x * inv, e1 = v0.y * inv, e2 = v0.z * inv, e3 = v0.w * inv;
                float e4 = v1.x * inv, e5 = v1.y * inv, e6 = v1.z * inv, e7 = v1.w * inv;
                US8 t;
                t.u[0] = f2bf(e0); t.u[1] = f2bf(e1); t.u[2] = f2bf(e2); t.u[3] = f2bf(e3);
                t.u[4] = f2bf(e4); t.u[5] = f2bf(e5); t.u[6] = f2bf(e6); t.u[7] = f2bf(e7);
                *reinterpret_cast<US8*>(ebf + (size_t)r * 512 + l * 8) = t;
                facc[0] += e0; facc[1] += e1; facc[2] += e2; facc[3] += e3;
                facc[4] += e4; facc[5] += e5; facc[6] += e6; facc[7] += e7;
            }
        }
    }
    *reinterpret_cast<float4*>(&part[w][l * 8]) =
        make_float4(facc[0], facc[1], facc[2], facc[3]);
    *reinterpret_cast<float4*>(&part[w][l * 8 + 4]) =
        make_float4(facc[4], facc[5], facc[6], facc[7]);
    if (l == 0) cnts[w] = cnt;
    __syncthreads();
    float s = part[0][tid] + part[1][tid] + part[2][tid] + part[3][tid]
            + part[4][tid] + part[5][tid] + part[6][tid] + part[7][tid];
    csum_bf[(size_t)c * 512 + tid] = f2bf(s);
    red[tid] = s * s;
    __syncthreads();
    for (int o = 256; o >= 1; o >>= 1) {
        if (tid < o) red[tid] += red[tid + o];
        __syncthreads();
    }
    if (tid == 0) {
        int ct = cnts[0] + cnts[1] + cnts[2] + cnts[3]
               + cnts[4] + cnts[5] + cnts[6] + cnts[7];
        counts[c] = ct;
        float nsq = red[0];
        normsq[c] = nsq;
        colscale[c] = wptr[0] / fmaxf(sqrtf(nsq), (float)ct * 1e-8f);
    }
}

// --- K2: GEMM (64 rows x 256 cols per block, 8 waves, dbuf gload_lds) ---
#define NKT 8

__global__ __launch_bounds__(512) void k_gemm(
        const unsigned short* __restrict__ ebf, const unsigned short* __restrict__ csum_bf,
        const int* __restrict__ y, const float* __restrict__ colscale,
        const float* __restrict__ normsq, const int* __restrict__ counts,
        const float* __restrict__ wptr, const float* __restrict__ bptr,
        float* __restrict__ colpart, float* __restrict__ selfpart, int C) {
    __shared__ __align__(16) unsigned short As[2][8 * 512];     // 2 x 8 KB
    __shared__ __align__(16) unsigned short Bs[2][32 * 512];    // 2 x 32 KB
    __shared__ float colsum[256];
    __shared__ float selfred[8];

    const int tid = threadIdx.x;
    const int l = tid & 63;
    const int w = tid >> 6;
    const int bx = blockIdx.x;
    const int r0 = bx * 64;
    const int rsub = l >> 2;
    const int kcs = ((l & 3) ^ ((l >> 3) & 3)) * 8;

    // A: 8 subtiles (kh*4 + rowblk); wave w stages subtile w.
    const unsigned short* srcA = ebf + (size_t)(r0 + (w & 3) * 16 + rsub) * 512
                               + (w >> 2) * 32 + kcs;
    // B: 32 subtiles (kh*16 + colblk); wave w stages subtiles w*4..w*4+3.
    const unsigned short* srcB[4];
#pragma unroll
    for (int i = 0; i < 4; ++i) {
        int st = w * 4 + i;
        srcB[i] = csum_bf + (size_t)((st & 15) * 16 + rsub) * 512 + (st >> 4) * 32 + kcs;
    }
    const int fro = (l & 15) * 32 + (((l >> 4) ^ ((l >> 1) & 3)) * 8);

    f32x4 acc[4][2];
#pragma unroll
    for (int m = 0; m < 4; ++m)
#pragma unroll
        for (int n = 0; n < 2; ++n) acc[m][n] = (f32x4){0.f, 0.f, 0.f, 0.f};

    gload_lds16(srcA, &As[0][w * 512]);
#pragma unroll
    for (int i = 0; i < 4; ++i) gload_lds16(srcB[i], &Bs[0][(w * 4 + i) * 512]);
    __syncthreads();

    int cur = 0;
    for (int kt = 0; kt < NKT; ++kt) {
        if (kt + 1 < NKT) {
            gload_lds16(srcA + (kt + 1) * 64, &As[cur ^ 1][w * 512]);
#pragma unroll
            for (int i = 0; i < 4; ++i)
                gload_lds16(srcB[i] + (kt + 1) * 64, &Bs[cur ^ 1][(w * 4 + i) * 512]);
        }
#pragma unroll
        for (int h = 0; h < 2; ++h) {
            bf16x8 af[4];
#pragma unroll
            for (int m = 0; m < 4; ++m)
                af[m] = *reinterpret_cast<const bf16x8*>(&As[cur][(h * 4 + m) * 512 + fro]);
#pragma unroll
            for (int n = 0; n < 2; ++n) {
                bf16x8 bv = *reinterpret_cast<const bf16x8*>(
                    &Bs[cur][(h * 16 + w * 2 + n) * 512 + fro]);
#pragma unroll
                for (int m = 0; m < 4; ++m)
                    acc[m][n] = __builtin_amdgcn_mfma_f32_16x16x32_bf16(af[m], bv, acc[m][n], 0, 0, 0);
            }
        }
        __syncthreads();
        cur ^= 1;
    }

    // epilogue: C/D layout col=lane&15, row=(lane>>4)*4+j; wave w -> cols w*32..+31
    float bv = bptr[0], wv = wptr[0];
    int lcol = l & 15, lrow4 = (l >> 4) * 4;
    float cs[2], nsq[2], cm1[2]; int cls[2];
#pragma unroll
    for (int n = 0; n < 2; ++n) {
        int c = w * 32 + n * 16 + lcol;
        cls[n] = c; cs[n] = colscale[c]; nsq[n] = normsq[c];
        cm1[n] = (float)(counts[c] - 1);
    }
    float colacc[2] = {0.f, 0.f};
    float selfacc = 0.f;
#pragma unroll
    for (int m = 0; m < 4; ++m) {
#pragma unroll
        for (int j = 0; j < 4; ++j) {
            int row = r0 + m * 16 + lrow4 + j;
            int yc = y[row];
#pragma unroll
            for (int n = 0; n < 2; ++n) {
                float dot = acc[m][n][j];
                float logit;
                if (yc == cls[n]) {
                    float un2 = fmaxf(nsq[n] - 2.f * dot + 1.f, 0.f);
                    float denom = fmaxf(sqrtf(un2), cm1[n] * 1e-8f);
                    logit = wv * (dot - 1.f) / denom + bv;
                    selfacc += logit;
                } else {
                    logit = dot * cs[n] + bv;
                }
                colacc[n] += __expf(logit);
            }
        }
    }
#pragma unroll
    for (int n = 0; n < 2; ++n) {
        float v = colacc[n];
        v += __shfl_xor(v, 16, 64);
        v += __shfl_xor(v, 32, 64);
        colacc[n] = v;
    }
    selfacc = waveReduceSum(selfacc);
    if (l < 16) {
#pragma unroll
        for (int n = 0; n < 2; ++n) colsum[w * 32 + n * 16 + l] = colacc[n];
    }
    if (l == 0) selfred[w] = selfacc;
    __syncthreads();
    if (tid < 256)
        colpart[(size_t)bx * 256 + tid] = colsum[tid];
    if (tid == 0)
        selfpart[bx] = selfred[0] + selfred[1] + selfred[2] + selfred[3]
                     + selfred[4] + selfred[5] + selfred[6] + selfred[7];
}

// --- K3: per-class reduce -> contrib[c] = counts[c]*log(sum over row tiles) ---
__global__ __launch_bounds__(64) void k_colreduce(
        const float* __restrict__ colpart, const int* __restrict__ counts,
        float* __restrict__ contrib, int nbx, int C) {
    int c = blockIdx.x, l = threadIdx.x;
    float s = 0.f;
    for (int i = l; i < nbx; i += 64) s += colpart[(size_t)i * C + c];
    s = waveReduceSum(s);
    if (l == 0) contrib[c] = (float)counts[c] * logf(s);
}

// --- K4: finalize: sum contribs minus self partials ---
__global__ __launch_bounds__(256) void k_final(
        const float* __restrict__ contrib, const float* __restrict__ selfpart,
        float* __restrict__ out, int nbx, int C) {
    __shared__ float lds[256];
    int tid = threadIdx.x;
    float v = (tid < C) ? contrib[tid] : 0.f;
    for (int i = tid; i < nbx; i += 256) v -= selfpart[i];
    lds[tid] = v;
    __syncthreads();
    for (int o = 128; o >= 1; o >>= 1) {
        if (tid < o) lds[tid] += lds[tid + o];
        __syncthreads();
    }
    if (tid == 0) out[0] = lds[0];
}

extern "C" void kernel_launch(void* const* d_in, const int* in_sizes, int n_in,
                              void* d_out, int out_size, void* d_ws, size_t ws_size,
                              hipStream_t stream) {
    const float* emb  = (const float*)d_in[0];
    const int*   y    = (const int*)d_in[1];
    const float* wptr = (const float*)d_in[2];
    const float* bptr = (const float*)d_in[3];
    float* out = (float*)d_out;
    int N = in_sizes[1];                      // 16384
    const int C = 256;
    int nbx = N / 64;                         // 256

    unsigned short* ebf     = (unsigned short*)d_ws;                 // N*512 bf16
    unsigned short* csum_bf = ebf + (size_t)N * 512;                 // C*512 bf16
    float* colpart  = (float*)(csum_bf + (size_t)C * 512);           // nbx*C
    float* selfpart = colpart + (size_t)nbx * C;                     // nbx
    float* normsq   = selfpart + nbx;                                // C
    float* colscale = normsq + C;                                    // C
    int*   counts   = (int*)(colscale + C);                          // C
    float* contrib  = (float*)(counts + C);                          // C

    k_centroid <<<C, 512, 0, stream>>>(emb, y, wptr, ebf, csum_bf, normsq,
                                       colscale, counts, N);
    k_gemm     <<<nbx, 512, 0, stream>>>(ebf, csum_bf, y, colscale, normsq, counts,
                                         wptr, bptr, colpart, selfpart, C);
    k_colreduce<<<C, 64, 0, stream>>>(colpart, counts, contrib, nbx, C);
    k_final    <<<1, 256, 0, stream>>>(contrib, selfpart, out, nbx, C);
}